// Round 4
// baseline (291.962 us; speedup 1.0000x reference)
//
#include <hip/hip_runtime.h>
#include <hip/hip_bf16.h>
#include <cstdint>
#include <cstddef>

#define NHEAD 12
#define TSEQ  4096
#define CDIM  768

typedef __attribute__((ext_vector_type(8))) short bf16x8;
typedef __attribute__((ext_vector_type(4))) float f32x4;
typedef __attribute__((ext_vector_type(16))) float f32x16;
typedef __attribute__((ext_vector_type(2))) unsigned int u32x2;

typedef __attribute__((address_space(1))) void gvoid;
typedef __attribute__((address_space(3))) void lvoid;

#define QSCALE 0.1803368801111204f   /* 0.125 * log2(e) */

static __device__ __forceinline__ unsigned short f2bf(float f) {
    union { float f; uint32_t u; } v; v.f = f;
    uint32_t u = v.u;
    u += 0x7fffu + ((u >> 16) & 1u);   // RNE
    return (unsigned short)(u >> 16);
}

static __device__ __forceinline__ f32x4 mfma16(bf16x8 a, bf16x8 b, f32x4 c) {
    return __builtin_amdgcn_mfma_f32_16x16x32_bf16(a, b, c, 0, 0, 0);
}
static __device__ __forceinline__ f32x16 mfma32(bf16x8 a, bf16x8 b, f32x16 c) {
    return __builtin_amdgcn_mfma_f32_32x32x16_bf16(a, b, c, 0, 0, 0);
}
static __device__ __forceinline__ unsigned cvt_pk_bf16(float lo, float hi) {
    unsigned r;
    asm("v_cvt_pk_bf16_f32 %0, %1, %2" : "=v"(r) : "v"(lo), "v"(hi));
    return r;
}

// ---------------- conversion kernels ----------------

__global__ void cvt_f32_bf16(const float* __restrict__ in, unsigned short* __restrict__ out, int n4) {
    int i = blockIdx.x * blockDim.x + threadIdx.x;
    int stride = gridDim.x * blockDim.x;
    for (int idx = i; idx < n4; idx += stride) {
        float4 v = reinterpret_cast<const float4*>(in)[idx];
        ushort4 o;
        o.x = f2bf(v.x); o.y = f2bf(v.y); o.z = f2bf(v.z); o.w = f2bf(v.w);
        reinterpret_cast<ushort4*>(out)[idx] = o;
    }
}

// W [K][N] f32  ->  Wt [N][K] bf16
__global__ void transpose_cvt(const float* __restrict__ W, unsigned short* __restrict__ Wt,
                              int K, int N) {
    __shared__ float tile[32][33];
    int n0 = blockIdx.x * 32;
    int k0 = blockIdx.y * 32;
    int tx = threadIdx.x & 31;
    int ty = threadIdx.x >> 5;   // 0..7
    #pragma unroll
    for (int r = ty; r < 32; r += 8)
        tile[r][tx] = W[(size_t)(k0 + r) * N + n0 + tx];
    __syncthreads();
    #pragma unroll
    for (int r = ty; r < 32; r += 8)
        Wt[(size_t)(n0 + r) * K + k0 + tx] = f2bf(tile[tx][r]);
}

// ---------------- GEMM core (A [M][K] bf16, Bt [N][K] bf16) ----------------
// MODE 0: qkv epilogue -> Q[h][t][d] (pre-scaled), K[h][t][d], Vt[h][d][t]
// MODE 1: proj epilogue -> Out f32 [M][N] (+bias)

template<int MODE>
__global__ __launch_bounds__(256)
void gemm_bt(const unsigned short* __restrict__ A,
             const unsigned short* __restrict__ Bt,
             const float* __restrict__ bias,
             unsigned short* __restrict__ Qb,
             unsigned short* __restrict__ Kb,
             unsigned short* __restrict__ Vt,
             float* __restrict__ Out,
             int M, int N, int K)
{
    __shared__ __align__(16) unsigned short As[128 * 32];
    __shared__ __align__(16) unsigned short Bs[128 * 32];

    const int tid  = threadIdx.x;
    const int lane = tid & 63;
    const int w    = tid >> 6;       // 4 waves
    const int wr   = w >> 1, wc = w & 1;
    const int row0 = blockIdx.x * 128;
    const int col0 = blockIdx.y * 128;
    const int l16  = lane & 15;
    const int lhi  = lane >> 4;

    f32x4 acc[4][4] = {};

    for (int k0 = 0; k0 < K; k0 += 32) {
        __syncthreads();
        #pragma unroll
        for (int r = 0; r < 2; ++r) {
            int b    = r * 4096 + w * 1024 + lane * 16;
            int trow = b >> 6;
            int koff = b & 63;
            const char* gA = (const char*)A  + ((size_t)(row0 + trow) * K + k0) * 2 + koff;
            const char* gB = (const char*)Bt + ((size_t)(col0 + trow) * K + k0) * 2 + koff;
            __builtin_amdgcn_global_load_lds((gvoid*)gA,
                (lvoid*)((char*)As + r * 4096 + w * 1024), 16, 0, 0);
            __builtin_amdgcn_global_load_lds((gvoid*)gB,
                (lvoid*)((char*)Bs + r * 4096 + w * 1024), 16, 0, 0);
        }
        __syncthreads();

        bf16x8 a[4], bfr[4];
        #pragma unroll
        for (int m = 0; m < 4; ++m) {
            int row = wr * 64 + m * 16 + l16;
            a[m] = *reinterpret_cast<const bf16x8*>(&As[row * 32 + lhi * 8]);
        }
        #pragma unroll
        for (int n = 0; n < 4; ++n) {
            int col = wc * 64 + n * 16 + l16;
            bfr[n] = *reinterpret_cast<const bf16x8*>(&Bs[col * 32 + lhi * 8]);
        }
        #pragma unroll
        for (int m = 0; m < 4; ++m)
            #pragma unroll
            for (int n = 0; n < 4; ++n)
                acc[m][n] = mfma16(a[m], bfr[n], acc[m][n]);
    }

    #pragma unroll
    for (int m = 0; m < 4; ++m) {
        int trow = row0 + wr * 64 + m * 16 + lhi * 4;
        #pragma unroll
        for (int n = 0; n < 4; ++n) {
            int ncol = col0 + wc * 64 + n * 16 + l16;
            float bv = bias[ncol];
            #pragma unroll
            for (int j = 0; j < 4; ++j) {
                float v = acc[m][n][j] + bv;
                int t = trow + j;
                if (MODE == 0) {
                    if (ncol < 768) {
                        int hh = ncol >> 6, d = ncol & 63;
                        Qb[((size_t)hh * TSEQ + t) * 64 + d] = f2bf(v * QSCALE);
                    } else if (ncol < 1536) {
                        int c = ncol - 768; int hh = c >> 6, d = c & 63;
                        Kb[((size_t)hh * TSEQ + t) * 64 + d] = f2bf(v);
                    } else {
                        int c = ncol - 1536; int hh = c >> 6, d = c & 63;
                        Vt[((size_t)hh * 64 + d) * TSEQ + t] = f2bf(v);
                    }
                } else {
                    Out[(size_t)t * N + ncol] = v;
                }
            }
        }
    }
}

// ---------------- flash attention (causal, swapped-operand, KV-split) -------
// grid: 1536 blocks = 128 q-blocks of 32 (desc order) x 12 heads.
// block = 256 threads = 4 waves, ALL on the same q-block; wave w processes
// KV tiles kt = w, w+4, ... (strided 4-way split of the KV axis). Each wave
// keeps private online-softmax state; final 3-way merge through LDS.
// Lane layout (32x32x16 mfma): col = lane&31 = q-index; softmax lane-local +
// one permlane32_swap. P->bf16 via cvt_pk + permlane32_swap (T12).

__global__ __launch_bounds__(256, 4)
void attn_fwd(const unsigned short* __restrict__ Qb,
              const unsigned short* __restrict__ Kb,
              const unsigned short* __restrict__ Vt,
              unsigned short* __restrict__ Y)
{
    __shared__ __align__(16) float Osh[3][32][64];   // [partial][elem][lane]
    __shared__ float Msh[3][64];
    __shared__ float Lsh[3][64];

    const int tid  = threadIdx.x;
    const int lane = tid & 63;
    const int w    = tid >> 6;
    const int l31  = lane & 31;
    const int hi   = lane >> 5;
    const int bid  = blockIdx.x;
    const int h    = bid % NHEAD;
    const int qb   = 127 - bid / NHEAD;     // biggest q-block first
    const int q0   = qb * 32;
    const int ntiles = q0 / 64 + 1;

    const unsigned short* Qh = Qb + (size_t)h * TSEQ * 64;
    const unsigned short* Kh = Kb + (size_t)h * TSEQ * 64;
    const unsigned short* Vh = Vt + (size_t)h * 64 * TSEQ;

    // Q^T B-fragments: Q[q0+l31][ks*16 + hi*8 + j]   (Q pre-scaled by QSCALE)
    bf16x8 qf[4];
    #pragma unroll
    for (int ks = 0; ks < 4; ++ks)
        qf[ks] = *reinterpret_cast<const bf16x8*>(
            &Qh[(size_t)(q0 + l31) * 64 + ks * 16 + hi * 8]);

    f32x16 o0 = {}, o1 = {};
    float mrun = -1e30f, lrun = 0.f;

    for (int kt = w; kt < ntiles; kt += 4) {
        const int kv0 = kt * 64;

        // K fragments (B of S^T)
        bf16x8 kf[2][4];
        #pragma unroll
        for (int sub = 0; sub < 2; ++sub)
            #pragma unroll
            for (int ks = 0; ks < 4; ++ks)
                kf[sub][ks] = *reinterpret_cast<const bf16x8*>(
                    &Kh[(size_t)(kv0 + sub * 32 + l31) * 64 + ks * 16 + hi * 8]);

        // V fragments (A of O^T) — issued early, consumed after softmax
        bf16x8 vf[2][4];
        #pragma unroll
        for (int d = 0; d < 2; ++d)
            #pragma unroll
            for (int ks = 0; ks < 4; ++ks)
                vf[d][ks] = *reinterpret_cast<const bf16x8*>(
                    &Vh[(size_t)(d * 32 + l31) * TSEQ + kv0 + ks * 16 + hi * 8]);

        // S^T = K · Q^T  (rows = kv, cols = q)
        f32x16 s0 = {}, s1 = {};
        #pragma unroll
        for (int ks = 0; ks < 4; ++ks) {
            s0 = mfma32(kf[0][ks], qf[ks], s0);
            s1 = mfma32(kf[1][ks], qf[ks], s1);
        }

        float sv[32];
        #pragma unroll
        for (int i = 0; i < 16; ++i) { sv[i] = s0[i]; sv[16 + i] = s1[i]; }

        if (kt == ntiles - 1) {           // diagonal tile: causal mask
            const int qrel = q0 + l31 - kv0;
            const int h4 = hi * 4;
            #pragma unroll
            for (int i = 0; i < 32; ++i) {
                int kvbase = (i >> 4) * 32 + (i & 3) + 8 * ((i >> 2) & 3);
                if (kvbase + h4 > qrel) sv[i] = -1e30f;
            }
        }

        // row max: in-lane tree + cross-half swap
        float t[16];
        #pragma unroll
        for (int i = 0; i < 16; ++i) t[i] = fmaxf(sv[i], sv[i + 16]);
        #pragma unroll
        for (int s = 8; s >= 1; s >>= 1)
            #pragma unroll
            for (int i = 0; i < s; ++i) t[i] = fmaxf(t[i], t[i + s]);
        float mx;
        {
            union { float f; unsigned u; } c; c.f = t[0];
            u32x2 r = __builtin_amdgcn_permlane32_swap(c.u, c.u, false, false);
            union { unsigned u; float f; } ra, rb; ra.u = r.x; rb.u = r.y;
            mx = fmaxf(ra.f, rb.f);
        }
        float mnew = fmaxf(mrun, mx);
        float corr = exp2f(mrun - mnew);
        mrun = mnew;

        float e[32];
        #pragma unroll
        for (int i = 0; i < 32; ++i) e[i] = exp2f(sv[i] - mnew);

        // row sum: in-lane tree + cross-half swap
        float u[16];
        #pragma unroll
        for (int i = 0; i < 16; ++i) u[i] = e[i] + e[i + 16];
        #pragma unroll
        for (int s = 8; s >= 1; s >>= 1)
            #pragma unroll
            for (int i = 0; i < s; ++i) u[i] += u[i + s];
        float ps;
        {
            union { float f; unsigned u; } c; c.f = u[0];
            u32x2 r = __builtin_amdgcn_permlane32_swap(c.u, c.u, false, false);
            union { unsigned u; float f; } ra, rb; ra.u = r.x; rb.u = r.y;
            ps = ra.f + rb.f;
        }
        lrun = lrun * corr + ps;

        // rescale O
        #pragma unroll
        for (int i = 0; i < 16; ++i) { o0[i] *= corr; o1[i] *= corr; }

        // pack P^T B-fragments: per 16-kv step, 4 cvt_pk + 2 permlane32_swap
        bf16x8 pw[4];
        #pragma unroll
        for (int ks = 0; ks < 4; ++ks) {
            const int eb = (ks >> 1) * 16 + (ks & 1) * 8;
            u32x2 r02 = __builtin_amdgcn_permlane32_swap(
                cvt_pk_bf16(e[eb + 0], e[eb + 1]), cvt_pk_bf16(e[eb + 4], e[eb + 5]),
                false, false);
            u32x2 r13 = __builtin_amdgcn_permlane32_swap(
                cvt_pk_bf16(e[eb + 2], e[eb + 3]), cvt_pk_bf16(e[eb + 6], e[eb + 7]),
                false, false);
            union { unsigned wd[4]; bf16x8 v; } pk;
            pk.wd[0] = r02.x; pk.wd[1] = r13.x; pk.wd[2] = r02.y; pk.wd[3] = r13.y;
            pw[ks] = pk.v;
        }

        // O^T += V^T · P^T
        #pragma unroll
        for (int ks = 0; ks < 4; ++ks) {
            o0 = mfma32(vf[0][ks], pw[ks], o0);
            o1 = mfma32(vf[1][ks], pw[ks], o1);
        }
    }

    // ---- KV-split merge through LDS (lane-contiguous layout) ----
    if (w > 0) {
        #pragma unroll
        for (int i = 0; i < 16; ++i) {
            Osh[w - 1][i][lane]      = o0[i];
            Osh[w - 1][16 + i][lane] = o1[i];
        }
        Msh[w - 1][lane] = mrun;
        Lsh[w - 1][lane] = lrun;
    }
    __syncthreads();
    if (w == 0) {
        #pragma unroll
        for (int p = 0; p < 3; ++p) {
            float mp = Msh[p][lane], lp = Lsh[p][lane];
            float mn = fmaxf(mrun, mp);
            float a = exp2f(mrun - mn), b = exp2f(mp - mn);
            #pragma unroll
            for (int i = 0; i < 16; ++i) {
                o0[i] = o0[i] * a + Osh[p][i][lane] * b;
                o1[i] = o1[i] * a + Osh[p][16 + i][lane] * b;
            }
            lrun = lrun * a + lp * b;
            mrun = mn;
        }

        // epilogue: y[t][h*64 + d], d = dsub*32 + (rr&3) + 8*(rr>>2) + 4*hi
        float inv = 1.0f / lrun;
        const int trow = q0 + l31;
        #pragma unroll
        for (int d = 0; d < 2; ++d) {
            #pragma unroll
            for (int p = 0; p < 8; ++p) {
                const int rr = p * 2;
                float v0 = (d ? o1 : o0)[rr] * inv;
                float v1 = (d ? o1 : o0)[rr + 1] * inv;
                int c = h * 64 + d * 32 + (rr & 3) + 8 * (rr >> 2) + hi * 4;
                unsigned wd = cvt_pk_bf16(v0, v1);
                *reinterpret_cast<unsigned*>(
                    const_cast<unsigned short*>(&Y[(size_t)trow * CDIM + c])) = wd;
            }
        }
    }
}

// ---------------- launch ----------------

extern "C" void kernel_launch(void* const* d_in, const int* in_sizes, int n_in,
                              void* d_out, int out_size, void* d_ws, size_t ws_size,
                              hipStream_t stream) {
    const float* x      = (const float*)d_in[0];
    const float* w_attn = (const float*)d_in[1];
    const float* b_attn = (const float*)d_in[2];
    const float* w_proj = (const float*)d_in[3];
    const float* b_proj = (const float*)d_in[4];
    float* out = (float*)d_out;

    char* ws = (char*)d_ws;
    unsigned short* xb  = (unsigned short*)(ws + 0);         // 4096*768
    unsigned short* WaT = (unsigned short*)(ws + 6291456);   // 2304*768
    unsigned short* WpT = (unsigned short*)(ws + 9830400);   // 768*768
    unsigned short* Qb  = (unsigned short*)(ws + 11010048);  // 12*4096*64
    unsigned short* Kb  = (unsigned short*)(ws + 17301504);  // 12*4096*64
    unsigned short* Vt  = (unsigned short*)(ws + 23592960);  // 12*64*4096
    unsigned short* Yb  = (unsigned short*)(ws + 29884416);  // 4096*768

    cvt_f32_bf16<<<2048, 256, 0, stream>>>(x, xb, TSEQ * CDIM / 4);
    transpose_cvt<<<dim3(2304 / 32, 768 / 32), 256, 0, stream>>>(w_attn, WaT, 768, 2304);
    transpose_cvt<<<dim3(768 / 32, 768 / 32), 256, 0, stream>>>(w_proj, WpT, 768, 768);

    gemm_bt<0><<<dim3(TSEQ / 128, 2304 / 128), 256, 0, stream>>>(
        xb, WaT, b_attn, Qb, Kb, Vt, nullptr, TSEQ, 2304, CDIM);

    attn_fwd<<<NHEAD * (TSEQ / 32), 256, 0, stream>>>(Qb, Kb, Vt, Yb);

    gemm_bt<1><<<dim3(TSEQ / 128, CDIM / 128), 256, 0, stream>>>(
        Yb, WpT, b_proj, nullptr, nullptr, nullptr, out, TSEQ, CDIM, CDIM);
}

// Round 5
// 231.352 us; speedup vs baseline: 1.2620x; 1.2620x over previous
//
#include <hip/hip_runtime.h>
#include <hip/hip_bf16.h>
#include <cstdint>
#include <cstddef>

#define NHEAD 12
#define TSEQ  4096
#define CDIM  768

typedef __attribute__((ext_vector_type(8))) short bf16x8;
typedef __attribute__((ext_vector_type(4))) float f32x4;
typedef __attribute__((ext_vector_type(16))) float f32x16;
typedef __attribute__((ext_vector_type(2))) unsigned int u32x2;

typedef __attribute__((address_space(1))) void gvoid;
typedef __attribute__((address_space(3))) void lvoid;

#define QSCALE 0.1803368801111204f   /* 0.125 * log2(e) */

static __device__ __forceinline__ unsigned short f2bf(float f) {
    union { float f; uint32_t u; } v; v.f = f;
    uint32_t u = v.u;
    u += 0x7fffu + ((u >> 16) & 1u);   // RNE
    return (unsigned short)(u >> 16);
}

static __device__ __forceinline__ f32x4 mfma16(bf16x8 a, bf16x8 b, f32x4 c) {
    return __builtin_amdgcn_mfma_f32_16x16x32_bf16(a, b, c, 0, 0, 0);
}
static __device__ __forceinline__ f32x16 mfma32(bf16x8 a, bf16x8 b, f32x16 c) {
    return __builtin_amdgcn_mfma_f32_32x32x16_bf16(a, b, c, 0, 0, 0);
}
static __device__ __forceinline__ unsigned cvt_pk_bf16(float lo, float hi) {
    unsigned r;
    asm("v_cvt_pk_bf16_f32 %0, %1, %2" : "=v"(r) : "v"(lo), "v"(hi));
    return r;
}

// ---------------- conversion kernels ----------------

__global__ void cvt_f32_bf16(const float* __restrict__ in, unsigned short* __restrict__ out, int n4) {
    int i = blockIdx.x * blockDim.x + threadIdx.x;
    int stride = gridDim.x * blockDim.x;
    for (int idx = i; idx < n4; idx += stride) {
        float4 v = reinterpret_cast<const float4*>(in)[idx];
        ushort4 o;
        o.x = f2bf(v.x); o.y = f2bf(v.y); o.z = f2bf(v.z); o.w = f2bf(v.w);
        reinterpret_cast<ushort4*>(out)[idx] = o;
    }
}

// W [K][N] f32  ->  Wt [N][K] bf16
__global__ void transpose_cvt(const float* __restrict__ W, unsigned short* __restrict__ Wt,
                              int K, int N) {
    __shared__ float tile[32][33];
    int n0 = blockIdx.x * 32;
    int k0 = blockIdx.y * 32;
    int tx = threadIdx.x & 31;
    int ty = threadIdx.x >> 5;   // 0..7
    #pragma unroll
    for (int r = ty; r < 32; r += 8)
        tile[r][tx] = W[(size_t)(k0 + r) * N + n0 + tx];
    __syncthreads();
    #pragma unroll
    for (int r = ty; r < 32; r += 8)
        Wt[(size_t)(n0 + r) * K + k0 + tx] = f2bf(tile[tx][r]);
}

// ---------------- GEMM core (A [M][K] bf16, Bt [N][K] bf16) ----------------
// MODE 0: qkv epilogue -> Q[h][t][d] (pre-scaled), K[h][t][d], Vt[h][d][t]
// MODE 1: proj epilogue -> Out f32 [M][N] (+bias)

template<int MODE>
__global__ __launch_bounds__(256)
void gemm_bt(const unsigned short* __restrict__ A,
             const unsigned short* __restrict__ Bt,
             const float* __restrict__ bias,
             unsigned short* __restrict__ Qb,
             unsigned short* __restrict__ Kb,
             unsigned short* __restrict__ Vt,
             float* __restrict__ Out,
             int M, int N, int K)
{
    __shared__ __align__(16) unsigned short As[128 * 32];
    __shared__ __align__(16) unsigned short Bs[128 * 32];

    const int tid  = threadIdx.x;
    const int lane = tid & 63;
    const int w    = tid >> 6;       // 4 waves
    const int wr   = w >> 1, wc = w & 1;
    const int row0 = blockIdx.x * 128;
    const int col0 = blockIdx.y * 128;
    const int l16  = lane & 15;
    const int lhi  = lane >> 4;

    f32x4 acc[4][4] = {};

    for (int k0 = 0; k0 < K; k0 += 32) {
        __syncthreads();
        #pragma unroll
        for (int r = 0; r < 2; ++r) {
            int b    = r * 4096 + w * 1024 + lane * 16;
            int trow = b >> 6;
            int koff = b & 63;
            const char* gA = (const char*)A  + ((size_t)(row0 + trow) * K + k0) * 2 + koff;
            const char* gB = (const char*)Bt + ((size_t)(col0 + trow) * K + k0) * 2 + koff;
            __builtin_amdgcn_global_load_lds((gvoid*)gA,
                (lvoid*)((char*)As + r * 4096 + w * 1024), 16, 0, 0);
            __builtin_amdgcn_global_load_lds((gvoid*)gB,
                (lvoid*)((char*)Bs + r * 4096 + w * 1024), 16, 0, 0);
        }
        __syncthreads();

        bf16x8 a[4], bfr[4];
        #pragma unroll
        for (int m = 0; m < 4; ++m) {
            int row = wr * 64 + m * 16 + l16;
            a[m] = *reinterpret_cast<const bf16x8*>(&As[row * 32 + lhi * 8]);
        }
        #pragma unroll
        for (int n = 0; n < 4; ++n) {
            int col = wc * 64 + n * 16 + l16;
            bfr[n] = *reinterpret_cast<const bf16x8*>(&Bs[col * 32 + lhi * 8]);
        }
        #pragma unroll
        for (int m = 0; m < 4; ++m)
            #pragma unroll
            for (int n = 0; n < 4; ++n)
                acc[m][n] = mfma16(a[m], bfr[n], acc[m][n]);
    }

    #pragma unroll
    for (int m = 0; m < 4; ++m) {
        int trow = row0 + wr * 64 + m * 16 + lhi * 4;
        #pragma unroll
        for (int n = 0; n < 4; ++n) {
            int ncol = col0 + wc * 64 + n * 16 + l16;
            float bv = bias[ncol];
            #pragma unroll
            for (int j = 0; j < 4; ++j) {
                float v = acc[m][n][j] + bv;
                int t = trow + j;
                if (MODE == 0) {
                    if (ncol < 768) {
                        int hh = ncol >> 6, d = ncol & 63;
                        Qb[((size_t)hh * TSEQ + t) * 64 + d] = f2bf(v * QSCALE);
                    } else if (ncol < 1536) {
                        int c = ncol - 768; int hh = c >> 6, d = c & 63;
                        Kb[((size_t)hh * TSEQ + t) * 64 + d] = f2bf(v);
                    } else {
                        int c = ncol - 1536; int hh = c >> 6, d = c & 63;
                        Vt[((size_t)hh * 64 + d) * TSEQ + t] = f2bf(v);
                    }
                } else {
                    Out[(size_t)t * N + ncol] = v;
                }
            }
        }
    }
}

// ---------------- flash attention (causal, swapped-operand, KV-split) -------
// grid: 1536 blocks = 128 q-blocks of 32 (desc order) x 12 heads.
// block = 256 threads = 4 waves, ALL on the same q-block; wave w processes
// KV tiles kt = w, w+4, ... (strided 4-way split). Private online-softmax
// state per wave (defer-max, THR=8 in log2 domain); 3-way LDS merge at end.
// launch_bounds(256,3): VGPR cap ~170 -- R3's (256,4) forced 64 VGPR = spills.

__global__ __launch_bounds__(256, 3)
void attn_fwd(const unsigned short* __restrict__ Qb,
              const unsigned short* __restrict__ Kb,
              const unsigned short* __restrict__ Vt,
              unsigned short* __restrict__ Y)
{
    __shared__ __align__(16) float Osh[3][32][64];   // [partial][elem][lane]
    __shared__ float Msh[3][64];
    __shared__ float Lsh[3][64];

    const int tid  = threadIdx.x;
    const int lane = tid & 63;
    const int w    = tid >> 6;
    const int l31  = lane & 31;
    const int hi   = lane >> 5;
    const int bid  = blockIdx.x;
    const int h    = bid % NHEAD;
    const int qb   = 127 - bid / NHEAD;     // biggest q-block first
    const int q0   = qb * 32;
    const int ntiles = q0 / 64 + 1;

    const unsigned short* Qh = Qb + (size_t)h * TSEQ * 64;
    const unsigned short* Kh = Kb + (size_t)h * TSEQ * 64;
    const unsigned short* Vh = Vt + (size_t)h * 64 * TSEQ;

    // Q^T B-fragments: Q[q0+l31][ks*16 + hi*8 + j]   (Q pre-scaled by QSCALE)
    bf16x8 qf[4];
    #pragma unroll
    for (int ks = 0; ks < 4; ++ks)
        qf[ks] = *reinterpret_cast<const bf16x8*>(
            &Qh[(size_t)(q0 + l31) * 64 + ks * 16 + hi * 8]);

    f32x16 o0 = {}, o1 = {};
    float mrun = -1e30f, lrun = 0.f;

    for (int kt = w; kt < ntiles; kt += 4) {
        const int kv0 = kt * 64;

        // K fragments (B of S^T)
        bf16x8 kf[2][4];
        #pragma unroll
        for (int sub = 0; sub < 2; ++sub)
            #pragma unroll
            for (int ks = 0; ks < 4; ++ks)
                kf[sub][ks] = *reinterpret_cast<const bf16x8*>(
                    &Kh[(size_t)(kv0 + sub * 32 + l31) * 64 + ks * 16 + hi * 8]);

        // V fragments (A of O^T) — issued early, consumed after softmax
        bf16x8 vf[2][4];
        #pragma unroll
        for (int d = 0; d < 2; ++d)
            #pragma unroll
            for (int ks = 0; ks < 4; ++ks)
                vf[d][ks] = *reinterpret_cast<const bf16x8*>(
                    &Vh[(size_t)(d * 32 + l31) * TSEQ + kv0 + ks * 16 + hi * 8]);

        // S^T = K · Q^T  (rows = kv, cols = q)
        f32x16 s0 = {}, s1 = {};
        #pragma unroll
        for (int ks = 0; ks < 4; ++ks) {
            s0 = mfma32(kf[0][ks], qf[ks], s0);
            s1 = mfma32(kf[1][ks], qf[ks], s1);
        }

        float sv[32];
        #pragma unroll
        for (int i = 0; i < 16; ++i) { sv[i] = s0[i]; sv[16 + i] = s1[i]; }

        if (kt == ntiles - 1) {           // diagonal tile: causal mask
            const int qrel = q0 + l31 - kv0;
            const int h4 = hi * 4;
            #pragma unroll
            for (int i = 0; i < 32; ++i) {
                int kvbase = (i >> 4) * 32 + (i & 3) + 8 * ((i >> 2) & 3);
                if (kvbase + h4 > qrel) sv[i] = -1e30f;
            }
        }

        // row max: in-lane tree + cross-half swap (off critical path when
        // defer-max takes the common branch)
        float t[16];
        #pragma unroll
        for (int i = 0; i < 16; ++i) t[i] = fmaxf(sv[i], sv[i + 16]);
        #pragma unroll
        for (int s = 8; s >= 1; s >>= 1)
            #pragma unroll
            for (int i = 0; i < s; ++i) t[i] = fmaxf(t[i], t[i + s]);
        float pmax;
        {
            union { float f; unsigned u; } c; c.f = t[0];
            u32x2 r = __builtin_amdgcn_permlane32_swap(c.u, c.u, false, false);
            union { unsigned u; float f; } ra, rb; ra.u = r.x; rb.u = r.y;
            pmax = fmaxf(ra.f, rb.f);
        }

        // defer-max (T13): only rescale when row max grows past mrun + 8
        if (!__all(pmax <= mrun + 8.0f)) {
            float mnew = fmaxf(mrun, pmax);
            float corr = exp2f(mrun - mnew);
            #pragma unroll
            for (int i = 0; i < 16; ++i) { o0[i] *= corr; o1[i] *= corr; }
            lrun *= corr;
            mrun = mnew;
        }

        float e[32];
        #pragma unroll
        for (int i = 0; i < 32; ++i) e[i] = exp2f(sv[i] - mrun);

        // row sum: in-lane tree + cross-half swap
        float u[16];
        #pragma unroll
        for (int i = 0; i < 16; ++i) u[i] = e[i] + e[i + 16];
        #pragma unroll
        for (int s = 8; s >= 1; s >>= 1)
            #pragma unroll
            for (int i = 0; i < s; ++i) u[i] += u[i + s];
        float ps;
        {
            union { float f; unsigned u; } c; c.f = u[0];
            u32x2 r = __builtin_amdgcn_permlane32_swap(c.u, c.u, false, false);
            union { unsigned u; float f; } ra, rb; ra.u = r.x; rb.u = r.y;
            ps = ra.f + rb.f;
        }
        lrun += ps;

        // pack P^T B-fragments: per 16-kv step, 4 cvt_pk + 2 permlane32_swap
        bf16x8 pw[4];
        #pragma unroll
        for (int ks = 0; ks < 4; ++ks) {
            const int eb = (ks >> 1) * 16 + (ks & 1) * 8;
            u32x2 r02 = __builtin_amdgcn_permlane32_swap(
                cvt_pk_bf16(e[eb + 0], e[eb + 1]), cvt_pk_bf16(e[eb + 4], e[eb + 5]),
                false, false);
            u32x2 r13 = __builtin_amdgcn_permlane32_swap(
                cvt_pk_bf16(e[eb + 2], e[eb + 3]), cvt_pk_bf16(e[eb + 6], e[eb + 7]),
                false, false);
            union { unsigned wd[4]; bf16x8 v; } pk;
            pk.wd[0] = r02.x; pk.wd[1] = r13.x; pk.wd[2] = r02.y; pk.wd[3] = r13.y;
            pw[ks] = pk.v;
        }

        // O^T += V^T · P^T
        #pragma unroll
        for (int ks = 0; ks < 4; ++ks) {
            o0 = mfma32(vf[0][ks], pw[ks], o0);
            o1 = mfma32(vf[1][ks], pw[ks], o1);
        }
    }

    // ---- KV-split merge through LDS (lane-contiguous layout) ----
    if (w > 0) {
        #pragma unroll
        for (int i = 0; i < 16; ++i) {
            Osh[w - 1][i][lane]      = o0[i];
            Osh[w - 1][16 + i][lane] = o1[i];
        }
        Msh[w - 1][lane] = mrun;
        Lsh[w - 1][lane] = lrun;
    }
    __syncthreads();
    if (w == 0) {
        #pragma unroll
        for (int p = 0; p < 3; ++p) {
            float mp = Msh[p][lane], lp = Lsh[p][lane];
            float mn = fmaxf(mrun, mp);
            float a = exp2f(mrun - mn), b = exp2f(mp - mn);
            #pragma unroll
            for (int i = 0; i < 16; ++i) {
                o0[i] = o0[i] * a + Osh[p][i][lane] * b;
                o1[i] = o1[i] * a + Osh[p][16 + i][lane] * b;
            }
            lrun = lrun * a + lp * b;
            mrun = mn;
        }

        // epilogue: y[t][h*64 + d], d = dsub*32 + (rr&3) + 8*(rr>>2) + 4*hi
        float inv = 1.0f / lrun;
        const int trow = q0 + l31;
        #pragma unroll
        for (int d = 0; d < 2; ++d) {
            #pragma unroll
            for (int p = 0; p < 8; ++p) {
                const int rr = p * 2;
                float v0 = (d ? o1 : o0)[rr] * inv;
                float v1 = (d ? o1 : o0)[rr + 1] * inv;
                int c = h * 64 + d * 32 + (rr & 3) + 8 * (rr >> 2) + hi * 4;
                unsigned wd = cvt_pk_bf16(v0, v1);
                *reinterpret_cast<unsigned*>(
                    const_cast<unsigned short*>(&Y[(size_t)trow * CDIM + c])) = wd;
            }
        }
    }
}

// ---------------- launch ----------------

extern "C" void kernel_launch(void* const* d_in, const int* in_sizes, int n_in,
                              void* d_out, int out_size, void* d_ws, size_t ws_size,
                              hipStream_t stream) {
    const float* x      = (const float*)d_in[0];
    const float* w_attn = (const float*)d_in[1];
    const float* b_attn = (const float*)d_in[2];
    const float* w_proj = (const float*)d_in[3];
    const float* b_proj = (const float*)d_in[4];
    float* out = (float*)d_out;

    char* ws = (char*)d_ws;
    unsigned short* xb  = (unsigned short*)(ws + 0);         // 4096*768
    unsigned short* WaT = (unsigned short*)(ws + 6291456);   // 2304*768
    unsigned short* WpT = (unsigned short*)(ws + 9830400);   // 768*768
    unsigned short* Qb  = (unsigned short*)(ws + 11010048);  // 12*4096*64
    unsigned short* Kb  = (unsigned short*)(ws + 17301504);  // 12*4096*64
    unsigned short* Vt  = (unsigned short*)(ws + 23592960);  // 12*64*4096
    unsigned short* Yb  = (unsigned short*)(ws + 29884416);  // 4096*768

    cvt_f32_bf16<<<2048, 256, 0, stream>>>(x, xb, TSEQ * CDIM / 4);
    transpose_cvt<<<dim3(2304 / 32, 768 / 32), 256, 0, stream>>>(w_attn, WaT, 768, 2304);
    transpose_cvt<<<dim3(768 / 32, 768 / 32), 256, 0, stream>>>(w_proj, WpT, 768, 768);

    gemm_bt<0><<<dim3(TSEQ / 128, 2304 / 128), 256, 0, stream>>>(
        xb, WaT, b_attn, Qb, Kb, Vt, nullptr, TSEQ, 2304, CDIM);

    attn_fwd<<<NHEAD * (TSEQ / 32), 256, 0, stream>>>(Qb, Kb, Vt, Yb);

    gemm_bt<1><<<dim3(TSEQ / 128, CDIM / 128), 256, 0, stream>>>(
        Yb, WpT, b_proj, nullptr, nullptr, nullptr, out, TSEQ, CDIM, CDIM);
}